// Round 12
// baseline (180.330 us; speedup 1.0000x reference)
//
#include <hip/hip_runtime.h>
#include <math.h>
#include <cstdint>
#include <cstddef>

typedef unsigned short u16;
typedef short bf16x8 __attribute__((ext_vector_type(8)));
typedef float f32x4 __attribute__((ext_vector_type(4)));
typedef u16 u16x8 __attribute__((ext_vector_type(8)));
typedef u16 u16x4 __attribute__((ext_vector_type(4)));

#define T_LEN 4096
#define NH 12
#define HD 64
#define DMODEL 768
#define GK 768                    // K dim for both GEMMs
#define QKV_STRIDE 6291456ul      // elems per q/k/v tensor = 8192*768

__device__ __forceinline__ u16 f2bf(float x) {
  union { float f; unsigned u; } v; v.f = x;
  unsigned r = v.u + 0x7fffu + ((v.u >> 16) & 1u);
  return (u16)(r >> 16);
}

__device__ __forceinline__ void async16(const u16* g, u16* l) {
  __builtin_amdgcn_global_load_lds(
      (const __attribute__((address_space(1))) unsigned int*)g,
      (__attribute__((address_space(3))) unsigned int*)l, 16, 0, 0);
}

// ---------------- fused fp32 -> bf16 conversion (x + 4 weights, one launch) ----------------
__global__ void cvt_all(const float* __restrict__ x,
                        const float* __restrict__ Wq, const float* __restrict__ Wk,
                        const float* __restrict__ Wv, const float* __restrict__ Wo,
                        u16* __restrict__ xb, u16* __restrict__ wqkv, u16* __restrict__ wo_b) {
  int bx = blockIdx.x;
  const float* s; u16* d; int base;
  if (bx < 6144)      { s = x;  d = xb;             base = bx; }
  else if (bx < 6720) { s = Wq; d = wqkv;           base = bx - 6144; }
  else if (bx < 7296) { s = Wk; d = wqkv + 589824;  base = bx - 6720; }
  else if (bx < 7872) { s = Wv; d = wqkv + 1179648; base = bx - 7296; }
  else                { s = Wo; d = wo_b;           base = bx - 7872; }
  int i = (base * 256 + (int)threadIdx.x) * 4;
  float4 v = *(const float4*)(s + i);
  u16x4 o;
  o[0] = f2bf(v.x); o[1] = f2bf(v.y); o[2] = f2bf(v.z); o[3] = f2bf(v.w);
  *(u16x4*)(d + i) = o;
}

// ---------------- GEMM: C = A[M,K] * B[N,K]^T + bias ----------------
// 64x128 tile, BK=32, 128 threads (2 waves, wave w owns 64x64 at cols w*64):
// per-wave MFMA:ds_read ratio identical to the 256-thread version (16:8 per
// K-iter) but grid doubles (6 blocks/CU resident) and each barrier drain
// stalls only 2 waves -> finer interleave of independent drains.
// async16 staging, XOR chunk swizzle LDS[row][c'] = global chunk c'^((row>>1)&3).
// 1-D grid, XCD swizzle: xcd = bid&7 owns a contiguous x-range (A L2 locality).
// EPI=0: Q/K bf16 row-major [8192,768] x2 tensors (bias0/bias1 select by bn0)
// EPI=1: fp32 direct store [8192,768] (+bias0)
// EPI=2: V bf16 block-transposed [b*12+h][t>>4][d][t&15], coalesced u16x4 stores
#define BN 128
#define BK 32

template <int EPI, int NX>
__global__ __launch_bounds__(128)
void gemm_bt(const u16* __restrict__ A, const u16* __restrict__ B,
             const float* __restrict__ bias0, const float* __restrict__ bias1,
             void* __restrict__ outp) {
  constexpr int PER = NX / 8;     // x-tiles per XCD group
  __shared__ __align__(16) u16 As[64 * BK];
  __shared__ __align__(16) u16 Bs[BN * BK];

  const int bid  = blockIdx.x;
  const int xcd  = bid & 7;
  const int slot = bid >> 3;
  const int bx   = xcd * PER + (slot % PER);
  const int by   = slot / PER;

  const int tid  = threadIdx.x;
  const int lane = tid & 63;
  const int wave = tid >> 6;          // 0..1
  const long am0 = (long)bx * 64;
  const long bn0 = (long)by * BN;
  const int r16 = lane & 15;
  const int kh  = lane >> 4;
  const int sw8 = (kh ^ ((r16 >> 1) & 3)) * 8;   // swizzled chunk offset for frag reads

  f32x4 acc[4][4] = {};

  // staging: lane l -> row l>>2, global chunk (l&3)^((l>>3)&3); LDS dest lane-linear
  const int srow   = lane >> 2;
  const int schunk = ((lane & 3) ^ ((lane >> 3) & 3)) * 8;
  const u16* Ag = A + (am0 + wave * 16 + srow) * GK + schunk;
  const u16* Bg = B + (bn0 + wave * 16 + srow) * GK + schunk;

  for (int kt = 0; kt < GK; kt += BK) {
    __syncthreads();
    // A: 64 rows, 2 instrs/wave (16 rows each)
    async16(Ag + kt, &As[(wave * 16) * BK]);
    async16(Ag + (size_t)32 * GK + kt, &As[(32 + wave * 16) * BK]);
    // B: 128 rows, 4 instrs/wave
#pragma unroll
    for (int s = 0; s < 4; s++)
      async16(Bg + (size_t)(s * 32) * GK + kt, &Bs[(s * 32 + wave * 16) * BK]);
    __syncthreads();
    bf16x8 af[4], bfr[4];
#pragma unroll
    for (int i = 0; i < 4; i++)
      af[i] = *(const bf16x8*)&As[(i * 16 + r16) * BK + sw8];
#pragma unroll
    for (int j = 0; j < 4; j++)
      bfr[j] = *(const bf16x8*)&Bs[(wave * 64 + j * 16 + r16) * BK + sw8];
#pragma unroll
    for (int i = 0; i < 4; i++)
#pragma unroll
      for (int j = 0; j < 4; j++)
        acc[i][j] = __builtin_amdgcn_mfma_f32_16x16x32_bf16(af[i], bfr[j], acc[i][j], 0, 0, 0);
  }

  const int m0 = (int)am0;            // wave covers all 64 rows, cols wave*64..+63

  if (EPI == 0) {
    // Q or K: row-major [8192][768], tensor selected by bn0
    const int tens = (int)(bn0 >= 768);
    const int c0 = (int)bn0 - tens * 768;
    const float* bp = tens ? bias1 : bias0;
    u16* outb = (u16*)outp + (size_t)tens * QKV_STRIDE;
#pragma unroll
    for (int j = 0; j < 4; j++) {
      int col = c0 + wave * 64 + j * 16 + r16;
      float bv = bp[col];
#pragma unroll
      for (int i = 0; i < 4; i++) {
#pragma unroll
        for (int r = 0; r < 4; r++) {
          int row = m0 + i * 16 + kh * 4 + r;
          outb[(size_t)row * DMODEL + col] = f2bf(acc[i][j][r] + bv);
        }
      }
    }
  } else if (EPI == 2) {
    // V: block-transposed [b*12+h][t>>4][d][t&15]
    u16* vtb = (u16*)outp;
    const int kr = kh * 4;
#pragma unroll
    for (int j = 0; j < 4; j++) {
      int cl = (int)bn0 + wave * 64 + j * 16;   // multiple of 16, lane-uniform
      int hj = cl >> 6;
      int dlane = (cl & 63) + r16;
      float bv = bias0[cl + r16];
#pragma unroll
      for (int i = 0; i < 4; i++) {
        int row0 = m0 + i * 16;
        int b_ = row0 >> 12;
        int tb = (row0 & 4095) >> 4;
        size_t base = (((size_t)(b_ * NH + hj) * 256 + tb) << 10) + dlane * 16 + kr;
        u16x4 pk;
#pragma unroll
        for (int r = 0; r < 4; r++) pk[r] = f2bf(acc[i][j][r] + bv);
        *(u16x4*)(vtb + base) = pk;
      }
    }
  } else {
    float* O = (float*)outp;
#pragma unroll
    for (int i = 0; i < 4; i++) {
#pragma unroll
      for (int r = 0; r < 4; r++) {
        int row = m0 + i * 16 + kh * 4 + r;
        float* orow = O + (size_t)row * DMODEL;
#pragma unroll
        for (int j = 0; j < 4; j++) {
          int col = (int)bn0 + wave * 64 + j * 16 + r16;
          orow[col] = acc[i][j][r] + bias0[col];
        }
      }
    }
  }
}

// ---------------- MFMA banded local attention ----------------
// 64 queries/block (4 waves x 16 queries). Q,K row-major [8192][768];
// V block-transposed [bh][tb][d][tl]. Per wave: 6 MFMA scores (16x48),
// masked softmax (intra-quad shfl reductions), P -> LDS (C-layout -> A-layout),
// 8 MFMA PV with V B-frags read directly from global. O staged through the
// wave-private Ps buffer for coalesced 128B-row stores. Out bf16 [8192][768].
#define PSS 72   // Ps row stride (u16): 144B, 16B-aligned, 2-way banks (free)

__global__ __launch_bounds__(256)
void attn_mfma(const u16* __restrict__ qkv, const u16* __restrict__ vt,
               u16* __restrict__ attn) {
  __shared__ __align__(16) u16 Ps[4][16 * PSS];   // 9216 B
  const int tid = threadIdx.x, lane = tid & 63, wave = tid >> 6;
  const int r16 = lane & 15, quad = lane >> 4;
  const int q0 = blockIdx.x * 64;
  const int h = blockIdx.y, b = blockIdx.z;
  const long rowbase = (long)b * T_LEN;
  const int hc = h * HD;
  const u16* Qg = qkv;
  const u16* Kg = qkv + QKV_STRIDE;
  const u16* Vh = vt + ((size_t)(b * NH + h)) * (256 * 1024);

  const int qbase = q0 + wave * 16;   // first query of this wave
  const int kb = qbase - 16;          // first key (mult of 16, may be <0)

  // Q A-frags: rows qbase+r16, dims quad*8 (+0 / +32)
  const u16* qrow = Qg + (rowbase + qbase + r16) * DMODEL + hc + quad * 8;
  bf16x8 qa0 = *(const bf16x8*)qrow;
  bf16x8 qa1 = *(const bf16x8*)(qrow + 32);

  // scores: 3 key tiles x (K=64 -> 2 mfma)
  f32x4 s[3];
#pragma unroll
  for (int t = 0; t < 3; t++) {
    const u16* krow = Kg + (rowbase + kb + t * 16 + r16) * DMODEL + hc + quad * 8;
    bf16x8 kf0 = *(const bf16x8*)krow;
    bf16x8 kf1 = *(const bf16x8*)(krow + 32);
    f32x4 a = {};
    a = __builtin_amdgcn_mfma_f32_16x16x32_bf16(qa0, kf0, a, 0, 0, 0);
    a = __builtin_amdgcn_mfma_f32_16x16x32_bf16(qa1, kf1, a, 0, 0, 0);
    s[t] = a;
  }

  // masked softmax per C-row (query = qbase + quad*4 + r), cols across quad lanes
  float pr[3][4];
#pragma unroll
  for (int r = 0; r < 4; r++) {
    const int qg = qbase + quad * 4 + r;
    float sc[3];
#pragma unroll
    for (int t = 0; t < 3; t++) {
      int key = kb + t * 16 + r16;
      bool ok = (key >= qg - 16) && (key <= qg + 16) && (key >= 0) && (key < T_LEN);
      sc[t] = ok ? s[t][r] * 0.125f : -INFINITY;
    }
    float mx = fmaxf(sc[0], fmaxf(sc[1], sc[2]));
    mx = fmaxf(mx, __shfl_xor(mx, 1));
    mx = fmaxf(mx, __shfl_xor(mx, 2));
    mx = fmaxf(mx, __shfl_xor(mx, 4));
    mx = fmaxf(mx, __shfl_xor(mx, 8));
    float e0 = __expf(sc[0] - mx), e1 = __expf(sc[1] - mx), e2 = __expf(sc[2] - mx);
    float l = e0 + e1 + e2;
    l += __shfl_xor(l, 1);
    l += __shfl_xor(l, 2);
    l += __shfl_xor(l, 4);
    l += __shfl_xor(l, 8);
    float inv = 1.0f / l;
    pr[0][r] = e0 * inv; pr[1][r] = e1 * inv; pr[2][r] = e2 * inv;
  }

  // P: C-layout -> LDS (rows=query, cols=key rel kb), zero pad cols 48..63
  u16* psw = &Ps[wave][0];
#pragma unroll
  for (int t = 0; t < 3; t++)
#pragma unroll
    for (int r = 0; r < 4; r++)
      psw[(quad * 4 + r) * PSS + t * 16 + r16] = f2bf(pr[t][r]);
#pragma unroll
  for (int r = 0; r < 4; r++)
    psw[(quad * 4 + r) * PSS + 48 + r16] = 0;

  // P A-frags (keys 0..31, 32..47+pad)
  bf16x8 pa0 = *(const bf16x8*)&psw[r16 * PSS + quad * 8];
  bf16x8 pa1 = *(const bf16x8*)&psw[r16 * PSS + 32 + quad * 8];

  // PV: 4 d-col tiles x 2 k-frags; V B-frags direct from transposed global
  const int kq1 = kb + quad * 8;
  const int kq2 = kb + 32 + quad * 8;
  const int o1 = (kq1 >> 4) * 1024 + (kq1 & 15);
  const int o2 = (kq2 >> 4) * 1024 + (kq2 & 15);
  f32x4 o[4];
#pragma unroll
  for (int c = 0; c < 4; c++) {
    const u16* vb = Vh + (16 * c + r16) * 16;
    bf16x8 v1 = *(const bf16x8*)(vb + o1);
    bf16x8 v2 = *(const bf16x8*)(vb + o2);
    f32x4 a = {};
    a = __builtin_amdgcn_mfma_f32_16x16x32_bf16(pa0, v1, a, 0, 0, 0);
    a = __builtin_amdgcn_mfma_f32_16x16x32_bf16(pa1, v2, a, 0, 0, 0);
    o[c] = a;
  }

  // O: stage through Ps (wave-private, P-frags already consumed), then
  // coalesced row stores: lane l handles rows l>>3 and 8+(l>>3), 16B each.
#pragma unroll
  for (int c = 0; c < 4; c++)
#pragma unroll
    for (int r = 0; r < 4; r++)
      psw[(quad * 4 + r) * PSS + 16 * c + r16] = f2bf(o[c][r]);
  {
    int rr = lane >> 3, cc = (lane & 7) * 8;
    u16x8 v0 = *(const u16x8*)&psw[rr * PSS + cc];
    u16x8 v1 = *(const u16x8*)&psw[(8 + rr) * PSS + cc];
    u16* ob = attn + (rowbase + qbase) * DMODEL + hc;
    *(u16x8*)(ob + (size_t)rr * DMODEL + cc) = v0;
    *(u16x8*)(ob + (size_t)(8 + rr) * DMODEL + cc) = v1;
  }
}

// ---------------- launch ----------------
extern "C" void kernel_launch(void* const* d_in, const int* in_sizes, int n_in,
                              void* d_out, int out_size, void* d_ws, size_t ws_size,
                              hipStream_t stream) {
  const float* x  = (const float*)d_in[0];
  const float* Wq = (const float*)d_in[1];
  const float* bq = (const float*)d_in[2];
  const float* Wk = (const float*)d_in[3];
  const float* bk = (const float*)d_in[4];
  const float* Wv = (const float*)d_in[5];
  const float* bv = (const float*)d_in[6];
  const float* Wo = (const float*)d_in[7];
  const float* bo = (const float*)d_in[8];
  float* out = (float*)d_out;
  char* ws = (char*)d_ws;

  u16* xb   = (u16*)(ws);                 // 8192*768 bf16
  u16* wqkv = (u16*)(ws + 12582912);      // 2304*768 bf16 (Wq,Wk,Wv rows)
  u16* wo_b = (u16*)(ws + 16121856);      // 768*768 bf16
  u16* qkv  = (u16*)(ws + 17301504);      // 3*6291456 bf16 (Q,K row-major; V transposed)
  u16* attnb = (u16*)(ws + 55050240);     // 8192*768 bf16

  cvt_all<<<8448, 256, 0, stream>>>(x, Wq, Wk, Wv, Wo, xb, wqkv, wo_b);

  // Q,K projection: 128 x-tiles x 12 y-tiles = 1536 blocks of 128 thr
  gemm_bt<0, 128><<<1536, 128, 0, stream>>>(xb, wqkv, bq, bk, (void*)qkv);
  // V projection: 128 x 6 = 768 blocks
  gemm_bt<2, 128><<<768, 128, 0, stream>>>(xb, wqkv + 1179648, bv, bv,
                                           (void*)(qkv + 2 * QKV_STRIDE));
  attn_mfma<<<dim3(64, 12, 2), 256, 0, stream>>>(qkv, qkv + 2 * QKV_STRIDE, attnb);
  // out projection: 128 x 6 = 768 blocks
  gemm_bt<1, 128><<<768, 128, 0, stream>>>(attnb, wo_b, bo, bo, (void*)out);
}

// Round 13
// 168.477 us; speedup vs baseline: 1.0704x; 1.0704x over previous
//
#include <hip/hip_runtime.h>
#include <math.h>
#include <cstdint>
#include <cstddef>

typedef unsigned short u16;
typedef short bf16x8 __attribute__((ext_vector_type(8)));
typedef float f32x4 __attribute__((ext_vector_type(4)));
typedef u16 u16x8 __attribute__((ext_vector_type(8)));
typedef u16 u16x4 __attribute__((ext_vector_type(4)));

#define T_LEN 4096
#define NH 12
#define HD 64
#define DMODEL 768
#define GK 768                    // K dim for both GEMMs
#define QKV_STRIDE 6291456ul      // elems per q/k/v tensor = 8192*768

__device__ __forceinline__ u16 f2bf(float x) {
  union { float f; unsigned u; } v; v.f = x;
  unsigned r = v.u + 0x7fffu + ((v.u >> 16) & 1u);
  return (u16)(r >> 16);
}

__device__ __forceinline__ void async16(const u16* g, u16* l) {
  __builtin_amdgcn_global_load_lds(
      (const __attribute__((address_space(1))) unsigned int*)g,
      (__attribute__((address_space(3))) unsigned int*)l, 16, 0, 0);
}

// ---------------- fused fp32 -> bf16 conversion (x + 4 weights, one launch) ----------------
__global__ void cvt_all(const float* __restrict__ x,
                        const float* __restrict__ Wq, const float* __restrict__ Wk,
                        const float* __restrict__ Wv, const float* __restrict__ Wo,
                        u16* __restrict__ xb, u16* __restrict__ wqkv, u16* __restrict__ wo_b) {
  int bx = blockIdx.x;
  const float* s; u16* d; int base;
  if (bx < 6144)      { s = x;  d = xb;             base = bx; }
  else if (bx < 6720) { s = Wq; d = wqkv;           base = bx - 6144; }
  else if (bx < 7296) { s = Wk; d = wqkv + 589824;  base = bx - 6720; }
  else if (bx < 7872) { s = Wv; d = wqkv + 1179648; base = bx - 7296; }
  else                { s = Wo; d = wo_b;           base = bx - 7872; }
  int i = (base * 256 + (int)threadIdx.x) * 4;
  float4 v = *(const float4*)(s + i);
  u16x4 o;
  o[0] = f2bf(v.x); o[1] = f2bf(v.y); o[2] = f2bf(v.z); o[3] = f2bf(v.w);
  *(u16x4*)(d + i) = o;
}

// ---------------- GEMM: C = A[M,K] * B[N,K]^T + bias ----------------
// R11 structure (best measured): 256 threads, BMt x 128 tile (BMt = MI*32),
// BK=32, 4 waves 2x2, async16 staging, XOR chunk swizzle
// LDS[row][c'] = global chunk c'^((row>>1)&3) -> conflict-free frag reads.
// 1-D grid, XCD swizzle: xcd = bid&7 owns a contiguous x-range (A L2 locality).
// EPI=0: Q/K bf16 row-major [8192,768] x2 (bias0/bias1 by bn0), via padded
//        LDS C-tile -> coalesced 256B row-segment stores (grid is 3 blocks/CU,
//        so the 48KB LDS total costs no occupancy).
// EPI=1: fp32 direct store [8192,768] (+bias0)
// EPI=2: V bf16 block-transposed [b*12+h][t>>4][d][t&15], coalesced u16x4 stores
#define BN 128
#define BK 32
#define CPAD 8   // C-tile row pad (u16) to spread LDS banks on readback

template <int EPI, int MI, int NX>
__global__ __launch_bounds__(256)
void gemm_bt(const u16* __restrict__ A, const u16* __restrict__ B,
             const float* __restrict__ bias0, const float* __restrict__ bias1,
             void* __restrict__ outp) {
  constexpr int BMt = MI * 32;
  constexpr int PER = NX / 8;     // x-tiles per XCD group
  __shared__ __align__(16) u16 As[BMt * BK];
  __shared__ __align__(16) u16 Bs[BN * BK];
  __shared__ __align__(16) u16 Cs[EPI == 0 ? BMt * (BN + CPAD) : 8];

  const int bid  = blockIdx.x;
  const int xcd  = bid & 7;
  const int slot = bid >> 3;
  const int bx   = xcd * PER + (slot % PER);
  const int by   = slot / PER;

  const int tid  = threadIdx.x;
  const int lane = tid & 63;
  const int wave = tid >> 6;
  const int wm = wave & 1, wn = wave >> 1;
  const long am0 = (long)bx * BMt;
  const long bn0 = (long)by * BN;
  const int r16 = lane & 15;
  const int kh  = lane >> 4;
  const int sw8 = (kh ^ ((r16 >> 1) & 3)) * 8;   // swizzled chunk offset for frag reads

  f32x4 acc[MI][4] = {};

  // staging: lane l -> row l>>2, global chunk (l&3)^((l>>3)&3); LDS dest lane-linear
  const int srow   = lane >> 2;
  const int schunk = ((lane & 3) ^ ((lane >> 3) & 3)) * 8;
  const u16* Ag = A + (am0 + wave * 16 + srow) * GK + schunk;
  const u16* Bg = B + (bn0 + wave * 16 + srow) * GK + schunk;
  u16* Bl0 = &Bs[(wave * 16) * BK];
  u16* Bl1 = &Bs[(64 + wave * 16) * BK];

  for (int kt = 0; kt < GK; kt += BK) {
    __syncthreads();
#pragma unroll
    for (int s = 0; s < MI / 2; s++)
      async16(Ag + (size_t)(s * 64) * GK + kt, &As[(s * 64 + wave * 16) * BK]);
    async16(Bg + kt, Bl0);
    async16(Bg + 64 * GK + kt, Bl1);
    __syncthreads();
    bf16x8 af[MI], bfr[4];
#pragma unroll
    for (int i = 0; i < MI; i++)
      af[i] = *(const bf16x8*)&As[(wm * MI * 16 + i * 16 + r16) * BK + sw8];
#pragma unroll
    for (int j = 0; j < 4; j++)
      bfr[j] = *(const bf16x8*)&Bs[(wn * 64 + j * 16 + r16) * BK + sw8];
#pragma unroll
    for (int i = 0; i < MI; i++)
#pragma unroll
      for (int j = 0; j < 4; j++)
        acc[i][j] = __builtin_amdgcn_mfma_f32_16x16x32_bf16(af[i], bfr[j], acc[i][j], 0, 0, 0);
  }

  const int m0 = (int)am0 + wm * MI * 16;   // global row base of this wave's subtile

  if (EPI == 0) {
    // Q or K: row-major [8192][768], tensor selected by bn0. LDS C-stage.
    const int tens = (int)(bn0 >= 768);
    const int c0 = (int)bn0 - tens * 768;
    const float* bp = tens ? bias1 : bias0;
    u16* outb = (u16*)outp + (size_t)tens * QKV_STRIDE;
    // 1) acc -> Cs (bf16) with bias
#pragma unroll
    for (int j = 0; j < 4; j++) {
      int lc = wn * 64 + j * 16 + r16;
      float bv = bp[c0 + lc];
#pragma unroll
      for (int i = 0; i < MI; i++) {
        int lr = wm * MI * 16 + i * 16 + kh * 4;
#pragma unroll
        for (int r = 0; r < 4; r++)
          Cs[(lr + r) * (BN + CPAD) + lc] = f2bf(acc[i][j][r] + bv);
      }
    }
    __syncthreads();
    // 2) coalesced store: BMt*16 16B-chunks (16/row), 256B contiguous per 16 lanes
#pragma unroll
    for (int z = 0; z < BMt / 16; z++) {
      int cidx = z * 256 + tid;
      int row = cidx >> 4, ch = (cidx & 15) * 8;
      uint4 val = *(const uint4*)&Cs[row * (BN + CPAD) + ch];
      *(uint4*)(outb + (size_t)(am0 + row) * DMODEL + c0 + ch) = val;
    }
  } else if (EPI == 2) {
    // V: block-transposed [b*12+h][t>>4][d][t&15]
    u16* vtb = (u16*)outp;
    const int kr = kh * 4;
#pragma unroll
    for (int j = 0; j < 4; j++) {
      int cl = (int)bn0 + wn * 64 + j * 16;   // multiple of 16, lane-uniform
      int hj = cl >> 6;
      int dlane = (cl & 63) + r16;
      float bv = bias0[cl + r16];
#pragma unroll
      for (int i = 0; i < MI; i++) {
        int row0 = m0 + i * 16;
        int b_ = row0 >> 12;
        int tb = (row0 & 4095) >> 4;
        size_t base = (((size_t)(b_ * NH + hj) * 256 + tb) << 10) + dlane * 16 + kr;
        u16x4 pk;
#pragma unroll
        for (int r = 0; r < 4; r++) pk[r] = f2bf(acc[i][j][r] + bv);
        *(u16x4*)(vtb + base) = pk;
      }
    }
  } else {
    float* O = (float*)outp;
#pragma unroll
    for (int i = 0; i < MI; i++) {
#pragma unroll
      for (int r = 0; r < 4; r++) {
        int row = m0 + i * 16 + kh * 4 + r;
        float* orow = O + (size_t)row * DMODEL;
#pragma unroll
        for (int j = 0; j < 4; j++) {
          int col = (int)bn0 + wn * 64 + j * 16 + r16;
          orow[col] = acc[i][j][r] + bias0[col];
        }
      }
    }
  }
}

// ---------------- MFMA banded local attention ----------------
// 64 queries/block (4 waves x 16 queries). Q,K row-major [8192][768];
// V block-transposed [bh][tb][d][tl]. Per wave: 6 MFMA scores (16x48),
// masked softmax (intra-quad shfl reductions), P -> LDS (C-layout -> A-layout),
// 8 MFMA PV with V B-frags read directly from global. O staged through the
// wave-private Ps buffer for coalesced 128B-row stores. Out bf16 [8192][768].
#define PSS 72   // Ps row stride (u16): 144B, 16B-aligned, 2-way banks (free)

__global__ __launch_bounds__(256)
void attn_mfma(const u16* __restrict__ qkv, const u16* __restrict__ vt,
               u16* __restrict__ attn) {
  __shared__ __align__(16) u16 Ps[4][16 * PSS];   // 9216 B
  const int tid = threadIdx.x, lane = tid & 63, wave = tid >> 6;
  const int r16 = lane & 15, quad = lane >> 4;
  const int q0 = blockIdx.x * 64;
  const int h = blockIdx.y, b = blockIdx.z;
  const long rowbase = (long)b * T_LEN;
  const int hc = h * HD;
  const u16* Qg = qkv;
  const u16* Kg = qkv + QKV_STRIDE;
  const u16* Vh = vt + ((size_t)(b * NH + h)) * (256 * 1024);

  const int qbase = q0 + wave * 16;   // first query of this wave
  const int kb = qbase - 16;          // first key (mult of 16, may be <0)

  // Q A-frags: rows qbase+r16, dims quad*8 (+0 / +32)
  const u16* qrow = Qg + (rowbase + qbase + r16) * DMODEL + hc + quad * 8;
  bf16x8 qa0 = *(const bf16x8*)qrow;
  bf16x8 qa1 = *(const bf16x8*)(qrow + 32);

  // scores: 3 key tiles x (K=64 -> 2 mfma)
  f32x4 s[3];
#pragma unroll
  for (int t = 0; t < 3; t++) {
    const u16* krow = Kg + (rowbase + kb + t * 16 + r16) * DMODEL + hc + quad * 8;
    bf16x8 kf0 = *(const bf16x8*)krow;
    bf16x8 kf1 = *(const bf16x8*)(krow + 32);
    f32x4 a = {};
    a = __builtin_amdgcn_mfma_f32_16x16x32_bf16(qa0, kf0, a, 0, 0, 0);
    a = __builtin_amdgcn_mfma_f32_16x16x32_bf16(qa1, kf1, a, 0, 0, 0);
    s[t] = a;
  }

  // masked softmax per C-row (query = qbase + quad*4 + r), cols across quad lanes
  float pr[3][4];
#pragma unroll
  for (int r = 0; r < 4; r++) {
    const int qg = qbase + quad * 4 + r;
    float sc[3];
#pragma unroll
    for (int t = 0; t < 3; t++) {
      int key = kb + t * 16 + r16;
      bool ok = (key >= qg - 16) && (key <= qg + 16) && (key >= 0) && (key < T_LEN);
      sc[t] = ok ? s[t][r] * 0.125f : -INFINITY;
    }
    float mx = fmaxf(sc[0], fmaxf(sc[1], sc[2]));
    mx = fmaxf(mx, __shfl_xor(mx, 1));
    mx = fmaxf(mx, __shfl_xor(mx, 2));
    mx = fmaxf(mx, __shfl_xor(mx, 4));
    mx = fmaxf(mx, __shfl_xor(mx, 8));
    float e0 = __expf(sc[0] - mx), e1 = __expf(sc[1] - mx), e2 = __expf(sc[2] - mx);
    float l = e0 + e1 + e2;
    l += __shfl_xor(l, 1);
    l += __shfl_xor(l, 2);
    l += __shfl_xor(l, 4);
    l += __shfl_xor(l, 8);
    float inv = 1.0f / l;
    pr[0][r] = e0 * inv; pr[1][r] = e1 * inv; pr[2][r] = e2 * inv;
  }

  // P: C-layout -> LDS (rows=query, cols=key rel kb), zero pad cols 48..63
  u16* psw = &Ps[wave][0];
#pragma unroll
  for (int t = 0; t < 3; t++)
#pragma unroll
    for (int r = 0; r < 4; r++)
      psw[(quad * 4 + r) * PSS + t * 16 + r16] = f2bf(pr[t][r]);
#pragma unroll
  for (int r = 0; r < 4; r++)
    psw[(quad * 4 + r) * PSS + 48 + r16] = 0;

  // P A-frags (keys 0..31, 32..47+pad)
  bf16x8 pa0 = *(const bf16x8*)&psw[r16 * PSS + quad * 8];
  bf16x8 pa1 = *(const bf16x8*)&psw[r16 * PSS + 32 + quad * 8];

  // PV: 4 d-col tiles x 2 k-frags; V B-frags direct from transposed global
  const int kq1 = kb + quad * 8;
  const int kq2 = kb + 32 + quad * 8;
  const int o1 = (kq1 >> 4) * 1024 + (kq1 & 15);
  const int o2 = (kq2 >> 4) * 1024 + (kq2 & 15);
  f32x4 o[4];
#pragma unroll
  for (int c = 0; c < 4; c++) {
    const u16* vb = Vh + (16 * c + r16) * 16;
    bf16x8 v1 = *(const bf16x8*)(vb + o1);
    bf16x8 v2 = *(const bf16x8*)(vb + o2);
    f32x4 a = {};
    a = __builtin_amdgcn_mfma_f32_16x16x32_bf16(pa0, v1, a, 0, 0, 0);
    a = __builtin_amdgcn_mfma_f32_16x16x32_bf16(pa1, v2, a, 0, 0, 0);
    o[c] = a;
  }

  // O: stage through Ps (wave-private, P-frags already consumed), then
  // coalesced row stores: lane l handles rows l>>3 and 8+(l>>3), 16B each.
#pragma unroll
  for (int c = 0; c < 4; c++)
#pragma unroll
    for (int r = 0; r < 4; r++)
      psw[(quad * 4 + r) * PSS + 16 * c + r16] = f2bf(o[c][r]);
  {
    int rr = lane >> 3, cc = (lane & 7) * 8;
    u16x8 v0 = *(const u16x8*)&psw[rr * PSS + cc];
    u16x8 v1 = *(const u16x8*)&psw[(8 + rr) * PSS + cc];
    u16* ob = attn + (rowbase + qbase) * DMODEL + hc;
    *(u16x8*)(ob + (size_t)rr * DMODEL + cc) = v0;
    *(u16x8*)(ob + (size_t)(8 + rr) * DMODEL + cc) = v1;
  }
}

// ---------------- launch ----------------
extern "C" void kernel_launch(void* const* d_in, const int* in_sizes, int n_in,
                              void* d_out, int out_size, void* d_ws, size_t ws_size,
                              hipStream_t stream) {
  const float* x  = (const float*)d_in[0];
  const float* Wq = (const float*)d_in[1];
  const float* bq = (const float*)d_in[2];
  const float* Wk = (const float*)d_in[3];
  const float* bk = (const float*)d_in[4];
  const float* Wv = (const float*)d_in[5];
  const float* bv = (const float*)d_in[6];
  const float* Wo = (const float*)d_in[7];
  const float* bo = (const float*)d_in[8];
  float* out = (float*)d_out;
  char* ws = (char*)d_ws;

  u16* xb   = (u16*)(ws);                 // 8192*768 bf16
  u16* wqkv = (u16*)(ws + 12582912);      // 2304*768 bf16 (Wq,Wk,Wv rows)
  u16* wo_b = (u16*)(ws + 16121856);      // 768*768 bf16
  u16* qkv  = (u16*)(ws + 17301504);      // 3*6291456 bf16 (Q,K row-major; V transposed)
  u16* attnb = (u16*)(ws + 55050240);     // 8192*768 bf16

  cvt_all<<<8448, 256, 0, stream>>>(x, Wq, Wk, Wv, Wo, xb, wqkv, wo_b);

  // Q,K projection: 64 x-tiles x 12 y-tiles = 768 blocks, XCD-swizzled
  gemm_bt<0, 4, 64><<<768, 256, 0, stream>>>(xb, wqkv, bq, bk, (void*)qkv);
  // V projection: 64 x 6 = 384 blocks
  gemm_bt<2, 4, 64><<<384, 256, 0, stream>>>(xb, wqkv + 1179648, bv, bv,
                                             (void*)(qkv + 2 * QKV_STRIDE));
  attn_mfma<<<dim3(64, 12, 2), 256, 0, stream>>>(qkv, qkv + 2 * QKV_STRIDE, attnb);
  // out projection: 128 x 6 = 768 blocks
  gemm_bt<1, 2, 128><<<768, 256, 0, stream>>>(attnb, wo_b, bo, bo, (void*)out);
}